// Round 10
// baseline (629.799 us; speedup 1.0000x reference)
//
#include <hip/hip_runtime.h>
#include <hip/hip_bf16.h>

#define BB 2
#define CC 512
#define HH 14
#define WW 14
#define PP 196
#define NSEQ 8
#define NSLICE 16                // worker WGs per row (32 ch each)
#define NWORK (14 * NSLICE)      // 224
#define FW 16                    // words per counter line (64B)

// counters: ucnt[(cell*NSLICE + w)*FW] counts worker waves (8 = E ready)
//           hcnt[cell*FW]              counts window waves (8 = h ready)

// ---------------------------------------------------------------------------
// prep: gemm_a (224 WGs) + transpose_wh (256 WGs) + counter zero (1 WG)
// ---------------------------------------------------------------------------
__global__ __launch_bounds__(256) void prep(
    const float* __restrict__ Wx, const float* __restrict__ X,
    const float* __restrict__ b_in, const float* __restrict__ Wh,
    float* __restrict__ A, float* __restrict__ WhT,
    unsigned* __restrict__ cnts) {
    __shared__ float Ws[32][33], Xs[32][33];
    int bid = blockIdx.x;
    int t = threadIdx.x;
    if (bid < 224) {
        int z = bid / 112, rem = bid % 112;
        int c0 = (rem % 16) * 32, p0 = (rem / 16) * 32;
        int tx = t % 32, ty = t / 32;
        int pl = (t % 16) * 2, cl = (t / 16) * 2;
        float acc[2][2] = {{0.f,0.f},{0.f,0.f}};
        for (int k0 = 0; k0 < CC; k0 += 32) {
            #pragma unroll
            for (int r = 0; r < 4; ++r)
                Ws[ty + 8*r][tx] = Wx[(size_t)(c0 + ty + 8*r) * CC + k0 + tx];
            #pragma unroll
            for (int r = 0; r < 4; ++r) {
                int p = p0 + tx, k = k0 + ty + 8*r;
                Xs[ty + 8*r][tx] = (p < PP) ? X[((size_t)z * CC + k) * PP + p] : 0.f;
            }
            __syncthreads();
            #pragma unroll
            for (int k = 0; k < 32; ++k) {
                float w0 = Ws[cl][k], w1 = Ws[cl+1][k];
                float x0 = Xs[k][pl], x1 = Xs[k][pl+1];
                acc[0][0] += w0*x0; acc[0][1] += w0*x1;
                acc[1][0] += w1*x0; acc[1][1] += w1*x1;
            }
            __syncthreads();
        }
        #pragma unroll
        for (int i = 0; i < 2; ++i)
            #pragma unroll
            for (int j = 0; j < 2; ++j) {
                int c = c0 + cl + i, p = p0 + pl + j;
                if (p < PP) A[((size_t)z * PP + p) * CC + c] = acc[i][j] + b_in[c];
            }
    } else if (bid < 480) {
        int tid = bid - 224;
        int c0 = (tid % 16) * 32, k0 = (tid / 16) * 32;
        int tx = t % 32, ty = t / 32;
        #pragma unroll
        for (int r = 0; r < 4; ++r)
            Ws[ty + 8*r][tx] = Wh[(size_t)(c0 + ty + 8*r) * CC + k0 + tx];
        __syncthreads();
        #pragma unroll
        for (int r = 0; r < 4; ++r)
            WhT[(size_t)(k0 + ty + 8*r) * CC + c0 + tx] = Ws[tx][ty + 8*r];
    } else {
        for (int i = t; i < (PP * NSLICE + PP) * FW; i += 256) cnts[i] = 0u;
    }
}

// ---------------------------------------------------------------------------
// sync primitives
// ---------------------------------------------------------------------------
__device__ __forceinline__ unsigned flag_ld(const unsigned* f) {
    return __hip_atomic_load(f, __ATOMIC_RELAXED, __HIP_MEMORY_SCOPE_AGENT);
}
__device__ __forceinline__ void store_wt(float* p, float v) {
    __hip_atomic_store(p, v, __ATOMIC_RELAXED, __HIP_MEMORY_SCOPE_AGENT);
}
// check 4 slice counters (stride FW) all >= 8, pipelined loads
__device__ __forceinline__ bool chk4(const unsigned* fb) {
    unsigned a = flag_ld(fb + 0*FW), b = flag_ld(fb + 1*FW);
    unsigned c = flag_ld(fb + 2*FW), d = flag_ld(fb + 3*FW);
    return (a >= 8u) & (b >= 8u) & (c >= 8u) & (d >= 8u);
}

// one window pixel for 8 channels (this wave's seq); E = exp(U) input
__device__ __forceinline__ void pix(const float4 E0, const float4 E1,
                                    const float* ar, const float* er, float* hacc) {
    float ee[8] = {E0.x,E0.y,E0.z,E0.w,E1.x,E1.y,E1.z,E1.w};
    float ds = 0.f, tl[8];
    #pragma unroll
    for (int j = 0; j < 8; ++j) {
        float sv = ar[j] + __logf(ee[j]);
        float pv = er[j] * ee[j];
        ds += fmaxf(pv, 1.0f);
        tl[j] = fmaxf(sv, 0.0f) * pv;
    }
    #pragma unroll
    for (int off = 32; off; off >>= 1) ds += __shfl_xor(ds, off, 64);
    float rd = 1.0f / ds;
    #pragma unroll
    for (int j = 0; j < 8; ++j) hacc[j] += tl[j] * rd;
}

// process n pixels at rowp + y*CC, 4-deep pipelined plain loads
__device__ __forceinline__ void proc_row(const float* __restrict__ rowp, int n,
                                         const float* ar, const float* er, float* hacc) {
    float4 cur[4][2];
    int y = 0, curn = (n < 4) ? n : 4;
    #pragma unroll
    for (int i = 0; i < 4; ++i) if (i < curn) {
        cur[i][0] = *(const float4*)(rowp + (size_t)i * CC);
        cur[i][1] = *(const float4*)(rowp + (size_t)i * CC + 256);
    }
    while (true) {
        int yn = y + curn;
        int rem = n - yn;
        int nextn = (rem < 4) ? rem : 4;
        float4 nxt[4][2];
        #pragma unroll
        for (int i = 0; i < 4; ++i) if (i < nextn) {
            nxt[i][0] = *(const float4*)(rowp + (size_t)(yn + i) * CC);
            nxt[i][1] = *(const float4*)(rowp + (size_t)(yn + i) * CC + 256);
        }
        #pragma unroll
        for (int i = 0; i < 4; ++i) if (i < curn)
            pix(cur[i][0], cur[i][1], ar, er, hacc);
        if (nextn <= 0) break;
        #pragma unroll
        for (int i = 0; i < 4; ++i) if (i < nextn) {
            cur[i][0] = nxt[i][0]; cur[i][1] = nxt[i][1];
        }
        curn = nextn; y = yn;
    }
}

// ---------------------------------------------------------------------------
// One kernel, two roles, ZERO barriers and ZERO LDS in both:
//   blockIdx 0..223   : workers (row=bid>>4, 32-ch slice; wave = 4 channels,
//                       k split across lanes, weights in VGPRs)
//   blockIdx 224..419 : per-cell window WGs (wave = seq, independent)
// ---------------------------------------------------------------------------
__global__ __launch_bounds__(512, 4) void rnn_dataflow(
    const float* __restrict__ A, const float* __restrict__ WhT,
    float* __restrict__ E, float* __restrict__ h_t,
    unsigned* __restrict__ ucnt, unsigned* __restrict__ hcnt) {
    int bid = blockIdx.x;
    int t = threadIdx.x;
    int lane = t & 63, wv = t >> 6;

    if (bid < NWORK) {
        // ================= worker: wave = 4 channels, lanes = k =============
        int px = bid >> 4, w = bid & 15;
        int c0 = w * 32 + wv * 4;
        // wreg[j][ci] = WhT[k(j)][c0+ci],  k(j) = (j>>2)*256 + 4*lane + (j&3)
        float wreg[8][4];
        #pragma unroll
        for (int j = 0; j < 8; ++j) {
            int k = (j >> 2) * 256 + 4 * lane + (j & 3);
            #pragma unroll
            for (int ci = 0; ci < 4; ++ci)
                wreg[j][ci] = WhT[(size_t)k * CC + c0 + ci];
        }
        __builtin_amdgcn_s_setprio(1);

        for (int py = 0; py < WW; ++py) {
            int cell = px * WW + py;
            if (cell == PP - 1) break;           // (13,13) has no consumer
            if (lane == 0) {
                while (flag_ld(hcnt + (size_t)cell * FW) < 8u)
                    __builtin_amdgcn_s_sleep(1);
            }
            asm volatile("" ::: "memory");

            // fused stage + matvec: h from global, perfectly coalesced
            const float* hb = h_t + (size_t)cell * (NSEQ * CC);
            float acc[4][8];
            #pragma unroll
            for (int ci = 0; ci < 4; ++ci)
                #pragma unroll
                for (int s = 0; s < 8; ++s) acc[ci][s] = 0.f;
            #pragma unroll
            for (int s = 0; s < 8; ++s) {
                float4 ha = *(const float4*)(hb + (size_t)s * CC + 4 * lane);
                float4 hc = *(const float4*)(hb + (size_t)s * CC + 256 + 4 * lane);
                float hh[8] = {ha.x,ha.y,ha.z,ha.w,hc.x,hc.y,hc.z,hc.w};
                #pragma unroll
                for (int j = 0; j < 8; ++j)
                    #pragma unroll
                    for (int ci = 0; ci < 4; ++ci)
                        acc[ci][s] += wreg[j][ci] * hh[j];
            }
            // butterfly over 64 k-lanes
            #pragma unroll
            for (int off = 1; off < 64; off <<= 1)
                #pragma unroll
                for (int ci = 0; ci < 4; ++ci)
                    #pragma unroll
                    for (int s = 0; s < 8; ++s)
                        acc[ci][s] += __shfl_xor(acc[ci][s], off, 64);
            // lane L<32 publishes (s = L>>2, c = c0 + (L&3))
            float v = 0.f;
            #pragma unroll
            for (int s = 0; s < 8; ++s)
                #pragma unroll
                for (int ci = 0; ci < 4; ++ci)
                    if (lane == s * 4 + ci) v = acc[ci][s];
            if (lane < 32) {
                int s = lane >> 2, c = c0 + (lane & 3);
                store_wt(&E[((size_t)s * PP + cell) * CC + c], __expf(v));
            }
            __builtin_amdgcn_s_waitcnt(0);
            asm volatile("" ::: "memory");
            if (lane == 0)
                atomicAdd(ucnt + ((size_t)cell * NSLICE + w) * FW, 1u);
        }
    } else {
        // ================= per-cell window WG (wave = seq) ==================
        int cell = bid - NWORK;
        int px = cell / WW, py = cell % WW;
        int s = wv, m = s >> 1, b = s & 1;
        int fi = (m & 2) ? (HH-1-px) : px;
        int fj = (m & 1) ? (WW-1-py) : py;
        int cb = lane * 4;

        const float* acur = A + ((size_t)b * PP + fi * WW + fj) * CC;
        float4 a0 = *(const float4*)(acur + cb);
        float4 a1 = *(const float4*)(acur + cb + 256);
        float ar[8] = {a0.x,a0.y,a0.z,a0.w,a1.x,a1.y,a1.z,a1.w};
        float er[8];
        #pragma unroll
        for (int j = 0; j < 8; ++j) er[j] = __expf(ar[j]);
        float hacc[8] = {0.f,0.f,0.f,0.f,0.f,0.f,0.f,0.f};

        const float* Eb = E + (size_t)s * PP * CC;

        // Phase 1 (slack >= 2): opportunistic rows, parallel polling.
        unsigned pend = 0u;
        for (int x = 0; x <= px; ++x) {
            int yl = (x <= px-2) ? py : ((x == px-1) ? py-1 : py-2);
            if (yl >= 0) pend |= (1u << x);
        }
        while (pend) {
            int r = lane >> 2, q = lane & 3;
            bool rdy = true;
            if (r <= px && (pend & (1u << r))) {
                int yl = (r <= px-2) ? py : ((r == px-1) ? py-1 : py-2);
                rdy = chk4(ucnt + ((size_t)(r * WW + yl) * NSLICE + q * 4) * FW);
            }
            unsigned long long bal = __ballot(rdy);
            unsigned newly = 0u, rem2 = pend;
            while (rem2) {
                int x = __ffs(rem2) - 1; rem2 &= rem2 - 1;
                if (((bal >> (4*x)) & 0xFull) == 0xFull) newly |= 1u << x;
            }
            if (!newly) { __builtin_amdgcn_s_sleep(1); continue; }
            asm volatile("" ::: "memory");
            unsigned go = newly;
            while (go) {
                int x = __ffs(go) - 1; go &= go - 1;
                int yl = (x <= px-2) ? py : ((x == px-1) ? py-1 : py-2);
                proc_row(Eb + (size_t)(x * WW) * CC + cb, yl + 1, ar, er, hacc);
            }
            pend &= ~newly;
        }

        // Phase 2: the two d-1 critical pixels, one merged poll.
        __builtin_amdgcn_s_setprio(1);
        if (px > 0 || py > 0) {
            int qN = (px-1) * WW + py, qW = px * WW + (py-1);
            while (true) {
                bool rdy = true;
                if (lane < 4) {
                    if (px > 0) rdy = chk4(ucnt + ((size_t)qN * NSLICE + lane * 4) * FW);
                } else if (lane < 8) {
                    if (py > 0) rdy = chk4(ucnt + ((size_t)qW * NSLICE + (lane-4) * 4) * FW);
                }
                if ((__ballot(rdy) & 0xFFull) == 0xFFull) break;
                __builtin_amdgcn_s_sleep(1);
            }
            asm volatile("" ::: "memory");
            if (px > 0) {
                const float4* ep = (const float4*)(Eb + (size_t)qN * CC + cb);
                pix(ep[0], ep[64], ar, er, hacc);
            }
            if (py > 0) {
                const float4* ep = (const float4*)(Eb + (size_t)qW * CC + cb);
                pix(ep[0], ep[64], ar, er, hacc);
            }
        }
        {   // self pixel: U=0 -> E=1
            float ds = 0.f, tl[8];
            #pragma unroll
            for (int j = 0; j < 8; ++j) {
                float pv = er[j];
                ds += fmaxf(pv, 1.0f);
                tl[j] = fmaxf(ar[j], 0.0f) * pv;
            }
            #pragma unroll
            for (int off = 32; off; off >>= 1) ds += __shfl_xor(ds, off, 64);
            float rd = 1.0f / ds;
            #pragma unroll
            for (int j = 0; j < 8; ++j) hacc[j] += tl[j] * rd;
        }

        // per-wave publish: contiguous WT stores + own drain + counter bump
        float* hp = h_t + ((size_t)cell * NSEQ + s) * CC;
        #pragma unroll
        for (int j = 0; j < 4; ++j) {
            store_wt(hp + cb + j,       hacc[j]);
            store_wt(hp + cb + 256 + j, hacc[4 + j]);
        }
        __builtin_amdgcn_s_waitcnt(0);
        asm volatile("" ::: "memory");
        if (lane == 0) atomicAdd(hcnt + (size_t)cell * FW, 1u);
    }
}

// ---------------------------------------------------------------------------
// gemm_y: Y[b][p][c] = sum_k Wo[c][k] * (sum_m h_t[p][2m+b][k]) + 4*b_out[c]
// ---------------------------------------------------------------------------
__global__ __launch_bounds__(256) void gemm_y(
    const float* __restrict__ Wo, const float* __restrict__ h_t,
    const float* __restrict__ b_out, float* __restrict__ Y) {
    __shared__ float Ws[32][33], Hs[32][33];
    int b  = blockIdx.z;
    int c0 = blockIdx.x * 32, p0 = blockIdx.y * 32;
    int t  = threadIdx.x;
    int tx = t % 32, ty = t / 32;
    int pl = (t % 16) * 2, cl = (t / 16) * 2;
    float acc[2][2] = {{0.f,0.f},{0.f,0.f}};
    for (int k0 = 0; k0 < CC; k0 += 32) {
        #pragma unroll
        for (int r = 0; r < 4; ++r)
            Ws[ty + 8*r][tx] = Wo[(size_t)(c0 + ty + 8*r) * CC + k0 + tx];
        #pragma unroll
        for (int r = 0; r < 4; ++r) {
            int p = p0 + ty + 8*r;
            float v = 0.f;
            if (p < PP) {
                size_t base = (size_t)p * NSEQ * CC + k0 + tx;
                v = h_t[base + (size_t)(0 + b) * CC]
                  + h_t[base + (size_t)(2 + b) * CC]
                  + h_t[base + (size_t)(4 + b) * CC]
                  + h_t[base + (size_t)(6 + b) * CC];
            }
            Hs[tx][ty + 8*r] = v;
        }
        __syncthreads();
        #pragma unroll
        for (int k = 0; k < 32; ++k) {
            float w0 = Ws[cl][k], w1 = Ws[cl+1][k];
            float h0 = Hs[k][pl], h1 = Hs[k][pl+1];
            acc[0][0] += w0*h0; acc[0][1] += w0*h1;
            acc[1][0] += w1*h0; acc[1][1] += w1*h1;
        }
        __syncthreads();
    }
    #pragma unroll
    for (int i = 0; i < 2; ++i)
        #pragma unroll
        for (int j = 0; j < 2; ++j) {
            int cc = c0 + cl + i, p = p0 + pl + j;
            if (p < PP) Y[((size_t)b * PP + p) * CC + cc] = acc[i][j] + 4.0f * b_out[cc];
        }
}

// ---------------------------------------------------------------------------
// softmax over channels -> out[b][c][p]
// ---------------------------------------------------------------------------
__global__ __launch_bounds__(256) void softmax_out(
    const float* __restrict__ Y, float* __restrict__ out) {
    int wave = threadIdx.x >> 6, lane = threadIdx.x & 63;
    int idx = blockIdx.x * 4 + wave;
    if (idx >= BB * PP) return;
    int b = idx / PP, p = idx % PP;
    const float* y = Y + ((size_t)b * PP + p) * CC;
    float v[8];
    float mx = -3.4e38f;
    #pragma unroll
    for (int j = 0; j < 8; ++j) { v[j] = y[lane + 64*j]; mx = fmaxf(mx, v[j]); }
    #pragma unroll
    for (int off = 32; off; off >>= 1) mx = fmaxf(mx, __shfl_xor(mx, off, 64));
    float sum = 0.f;
    #pragma unroll
    for (int j = 0; j < 8; ++j) { v[j] = expf(v[j] - mx); sum += v[j]; }
    #pragma unroll
    for (int off = 32; off; off >>= 1) sum += __shfl_xor(sum, off, 64);
    float r = 1.0f / sum;
    #pragma unroll
    for (int j = 0; j < 8; ++j)
        out[((size_t)b * CC + lane + 64*j) * PP + p] = v[j] * r;
}

// ---------------------------------------------------------------------------
extern "C" void kernel_launch(void* const* d_in, const int* in_sizes, int n_in,
                              void* d_out, int out_size, void* d_ws, size_t ws_size,
                              hipStream_t stream) {
    const float* X     = (const float*)d_in[0];
    const float* Wx    = (const float*)d_in[1];
    const float* Wh    = (const float*)d_in[2];
    const float* b_in  = (const float*)d_in[3];
    const float* Wo    = (const float*)d_in[4];
    const float* b_out = (const float*)d_in[5];
    float* out = (float*)d_out;

    float* ws  = (float*)d_ws;
    float* WhT = ws;                        // 262144
    float* A   = WhT + 262144;              // 200704
    float* E   = A   + 200704;              // 802816  [s][cell][c] = exp(U)
    float* h_t = E   + 802816;              // 802816  [cell][s][c]
    float* Y   = h_t + 802816;              // 200704
    unsigned* ucnt = (unsigned*)(Y + 200704);       // PP*NSLICE*FW
    unsigned* hcnt = ucnt + PP * NSLICE * FW;       // PP*FW

    hipLaunchKernelGGL(prep, dim3(481), dim3(256), 0, stream,
                       Wx, X, b_in, Wh, A, WhT, ucnt);
    hipLaunchKernelGGL(rnn_dataflow, dim3(NWORK + PP), dim3(512), 0, stream,
                       A, WhT, E, h_t, ucnt, hcnt);
    hipLaunchKernelGGL(gemm_y, dim3(16, 7, 2), dim3(256), 0, stream, Wo, h_t, b_out, Y);
    hipLaunchKernelGGL(softmax_out, dim3(98), dim3(256), 0, stream, Y, out);
}

// Round 11
// 542.522 us; speedup vs baseline: 1.1609x; 1.1609x over previous
//
#include <hip/hip_runtime.h>
#include <hip/hip_bf16.h>

#define BB 2
#define CC 512
#define HH 14
#define WW 14
#define PP 196
#define NSEQ 8
#define NSLICE 16                // worker WGs per row (32 ch each)
#define NWORK (14 * NSLICE)      // 224
#define FW 16                    // flag words per cell (one 64B line)

// ---------------------------------------------------------------------------
// prep: gemm_a (224 WGs) + transpose_wh (256 WGs) + flag zero (1 WG)
// ---------------------------------------------------------------------------
__global__ __launch_bounds__(256) void prep(
    const float* __restrict__ Wx, const float* __restrict__ X,
    const float* __restrict__ b_in, const float* __restrict__ Wh,
    float* __restrict__ A, float* __restrict__ WhT,
    unsigned* __restrict__ flags /* uflag then hcnt, contiguous */) {
    __shared__ float Ws[32][33], Xs[32][33];
    int bid = blockIdx.x;
    int t = threadIdx.x;
    if (bid < 224) {
        int z = bid / 112, rem = bid % 112;
        int c0 = (rem % 16) * 32, p0 = (rem / 16) * 32;
        int tx = t % 32, ty = t / 32;
        int pl = (t % 16) * 2, cl = (t / 16) * 2;
        float acc[2][2] = {{0.f,0.f},{0.f,0.f}};
        for (int k0 = 0; k0 < CC; k0 += 32) {
            #pragma unroll
            for (int r = 0; r < 4; ++r)
                Ws[ty + 8*r][tx] = Wx[(size_t)(c0 + ty + 8*r) * CC + k0 + tx];
            #pragma unroll
            for (int r = 0; r < 4; ++r) {
                int p = p0 + tx, k = k0 + ty + 8*r;
                Xs[ty + 8*r][tx] = (p < PP) ? X[((size_t)z * CC + k) * PP + p] : 0.f;
            }
            __syncthreads();
            #pragma unroll
            for (int k = 0; k < 32; ++k) {
                float w0 = Ws[cl][k], w1 = Ws[cl+1][k];
                float x0 = Xs[k][pl], x1 = Xs[k][pl+1];
                acc[0][0] += w0*x0; acc[0][1] += w0*x1;
                acc[1][0] += w1*x0; acc[1][1] += w1*x1;
            }
            __syncthreads();
        }
        #pragma unroll
        for (int i = 0; i < 2; ++i)
            #pragma unroll
            for (int j = 0; j < 2; ++j) {
                int c = c0 + cl + i, p = p0 + pl + j;
                if (p < PP) A[((size_t)z * PP + p) * CC + c] = acc[i][j] + b_in[c];
            }
    } else if (bid < 480) {
        int tid = bid - 224;
        int c0 = (tid % 16) * 32, k0 = (tid / 16) * 32;
        int tx = t % 32, ty = t / 32;
        #pragma unroll
        for (int r = 0; r < 4; ++r)
            Ws[ty + 8*r][tx] = Wh[(size_t)(c0 + ty + 8*r) * CC + k0 + tx];
        __syncthreads();
        #pragma unroll
        for (int r = 0; r < 4; ++r)
            WhT[(size_t)(k0 + ty + 8*r) * CC + c0 + tx] = Ws[tx][ty + 8*r];
    } else {
        for (int i = t; i < 2 * PP * FW; i += 256) flags[i] = 0u;
    }
}

// ---------------------------------------------------------------------------
// sync primitives
// ---------------------------------------------------------------------------
__device__ __forceinline__ unsigned flag_ld(const unsigned* f) {
    return __hip_atomic_load(f, __ATOMIC_RELAXED, __HIP_MEMORY_SCOPE_AGENT);
}
__device__ __forceinline__ void flag_st(unsigned* f) {
    __hip_atomic_store(f, 1u, __ATOMIC_RELAXED, __HIP_MEMORY_SCOPE_AGENT);
}
__device__ __forceinline__ void store_wt(float* p, float v) {
    __hip_atomic_store(p, v, __ATOMIC_RELAXED, __HIP_MEMORY_SCOPE_AGENT);
}
// check 4 slice flags within a cell's 64B flag line
__device__ __forceinline__ bool chk4(const unsigned* fb) {
    unsigned a = flag_ld(fb + 0), b = flag_ld(fb + 1);
    unsigned c = flag_ld(fb + 2), d = flag_ld(fb + 3);
    return (a & b & c & d) != 0u;
}

// one window pixel for 8 channels (this wave's seq); E = exp(U) input
__device__ __forceinline__ void pix(const float4 E0, const float4 E1,
                                    const float* ar, const float* er, float* hacc) {
    float ee[8] = {E0.x,E0.y,E0.z,E0.w,E1.x,E1.y,E1.z,E1.w};
    float ds = 0.f, tl[8];
    #pragma unroll
    for (int j = 0; j < 8; ++j) {
        float sv = ar[j] + __logf(ee[j]);
        float pv = er[j] * ee[j];
        ds += fmaxf(pv, 1.0f);
        tl[j] = fmaxf(sv, 0.0f) * pv;
    }
    #pragma unroll
    for (int off = 32; off; off >>= 1) ds += __shfl_xor(ds, off, 64);
    float rd = 1.0f / ds;
    #pragma unroll
    for (int j = 0; j < 8; ++j) hacc[j] += tl[j] * rd;
}

// process n pixels at rowp + y*CC, 4-deep pipelined plain loads
__device__ __forceinline__ void proc_row(const float* __restrict__ rowp, int n,
                                         const float* ar, const float* er, float* hacc) {
    float4 cur[4][2];
    int y = 0, curn = (n < 4) ? n : 4;
    #pragma unroll
    for (int i = 0; i < 4; ++i) if (i < curn) {
        cur[i][0] = *(const float4*)(rowp + (size_t)i * CC);
        cur[i][1] = *(const float4*)(rowp + (size_t)i * CC + 256);
    }
    while (true) {
        int yn = y + curn;
        int rem = n - yn;
        int nextn = (rem < 4) ? rem : 4;
        float4 nxt[4][2];
        #pragma unroll
        for (int i = 0; i < 4; ++i) if (i < nextn) {
            nxt[i][0] = *(const float4*)(rowp + (size_t)(yn + i) * CC);
            nxt[i][1] = *(const float4*)(rowp + (size_t)(yn + i) * CC + 256);
        }
        #pragma unroll
        for (int i = 0; i < 4; ++i) if (i < curn)
            pix(cur[i][0], cur[i][1], ar, er, hacc);
        if (nextn <= 0) break;
        #pragma unroll
        for (int i = 0; i < 4; ++i) if (i < nextn) {
            cur[i][0] = nxt[i][0]; cur[i][1] = nxt[i][1];
        }
        curn = nextn; y = yn;
    }
}

// ---------------------------------------------------------------------------
// One kernel, two roles:
//   blockIdx 0..223   : persistent matvec workers (row = bid>>4, 32-ch slice)
//   blockIdx 224..419 : per-cell window WGs (wave = seq; wave 0 is the sole
//                       fabric poller for phase 1, mailbox in LDS)
// ---------------------------------------------------------------------------
__global__ __launch_bounds__(512, 4) void rnn_dataflow(
    const float* __restrict__ A, const float* __restrict__ WhT,
    float* __restrict__ E, float* __restrict__ h_t,
    unsigned* __restrict__ uflag, unsigned* __restrict__ hcnt) {
    __shared__ float smem[CC * 9];    // worker: hT[k][s] stride 9
    __shared__ float ured[32 * 9];
    __shared__ unsigned mbox;         // window: ready-rows bitmap
    int bid = blockIdx.x;
    int t = threadIdx.x;
    int lane = t & 63, wv = t >> 6;

    if (bid < NWORK) {
        // ================= persistent worker =================
        int px = bid >> 4, w = bid & 15;
        int ksub = t & 31, quad = t >> 5;        // 32 k-lanes x 16 c-pairs
        int c0 = w * 32 + quad * 2;
        float wreg[2][16];
        #pragma unroll
        for (int ci = 0; ci < 2; ++ci)
            #pragma unroll
            for (int j = 0; j < 16; ++j)
                wreg[ci][j] = WhT[(size_t)(ksub + 32*j) * CC + c0 + ci];
        __builtin_amdgcn_s_setprio(1);

        for (int py = 0; py < WW; ++py) {
            int cell = px * WW + py;
            if (cell == PP - 1) break;           // (13,13) has no consumer
            if (t == 0) {
                while (flag_ld(hcnt + (size_t)cell * FW) < 8u)
                    __builtin_amdgcn_s_sleep(1);
            }
            __syncthreads();
            asm volatile("" ::: "memory");

            // stage h_t[cell][s][k] -> smem[k*9+s] (coalesced loads, CF writes)
            const float* hp = h_t + (size_t)cell * (CC * NSEQ);
            #pragma unroll
            for (int s = 0; s < 8; ++s)
                smem[t * 9 + s] = hp[(size_t)s * CC + t];
            __syncthreads();

            float acc[2][8];
            #pragma unroll
            for (int ci = 0; ci < 2; ++ci)
                #pragma unroll
                for (int ss = 0; ss < 8; ++ss) acc[ci][ss] = 0.f;
            #pragma unroll
            for (int j = 0; j < 16; ++j) {
                int k = ksub + 32*j;
                float hh[8];
                #pragma unroll
                for (int ss = 0; ss < 8; ++ss) hh[ss] = smem[k * 9 + ss];
                #pragma unroll
                for (int ci = 0; ci < 2; ++ci) {
                    float wvv = wreg[ci][j];
                    #pragma unroll
                    for (int ss = 0; ss < 8; ++ss) acc[ci][ss] += wvv * hh[ss];
                }
            }
            #pragma unroll
            for (int off = 1; off < 32; off <<= 1)
                #pragma unroll
                for (int ci = 0; ci < 2; ++ci)
                    #pragma unroll
                    for (int ss = 0; ss < 8; ++ss)
                        acc[ci][ss] += __shfl_xor(acc[ci][ss], off, 64);
            if (ksub == 0)
                #pragma unroll
                for (int ci = 0; ci < 2; ++ci)
                    #pragma unroll
                    for (int ss = 0; ss < 8; ++ss)
                        ured[(quad*2 + ci) * 9 + ss] = acc[ci][ss];
            __syncthreads();
            if (t < 256) {       // publish E = exp(U), coalesced WT dword stores
                int s = t >> 5, cl = t & 31;
                store_wt(&E[((size_t)s * PP + cell) * CC + w*32 + cl],
                         __expf(ured[cl * 9 + s]));
            }
            __syncthreads();     // all waves drained vmcnt before barrier
            if (t == 0) flag_st(uflag + (size_t)cell * FW + w);
        }
    } else {
        // ================= per-cell window WG (wave = seq) ==================
        int cell = bid - NWORK;
        int px = cell / WW, py = cell % WW;
        int s = wv, m = s >> 1, b = s & 1;
        int fi = (m & 2) ? (HH-1-px) : px;
        int fj = (m & 1) ? (WW-1-py) : py;
        int cb = lane * 4;

        if (t == 0) mbox = 0u;
        __syncthreads();          // once, at WG start (long before deps ready)

        const float* acur = A + ((size_t)b * PP + fi * WW + fj) * CC;
        float4 a0 = *(const float4*)(acur + cb);
        float4 a1 = *(const float4*)(acur + cb + 256);
        float ar[8] = {a0.x,a0.y,a0.z,a0.w,a1.x,a1.y,a1.z,a1.w};
        float er[8];
        #pragma unroll
        for (int j = 0; j < 8; ++j) er[j] = __expf(ar[j]);
        float hacc[8] = {0.f,0.f,0.f,0.f,0.f,0.f,0.f,0.f};

        const float* Eb = E + (size_t)s * PP * CC;

        // Phase 1 (slack >= 2): wave 0 polls fabric + publishes LDS mailbox;
        // waves 1-7 spin on LDS only (no fabric poll traffic).
        unsigned pend = 0u;
        for (int x = 0; x <= px; ++x) {
            int yl = (x <= px-2) ? py : ((x == px-1) ? py-1 : py-2);
            if (yl >= 0) pend |= (1u << x);
        }
        if (wv == 0) {
            unsigned done = 0u;
            while (pend) {
                int r = lane >> 2, q = lane & 3;
                bool rdy = true;
                if (r <= px && (pend & (1u << r))) {
                    int yl = (r <= px-2) ? py : ((r == px-1) ? py-1 : py-2);
                    rdy = chk4(uflag + (size_t)(r * WW + yl) * FW + q * 4);
                }
                unsigned long long bal = __ballot(rdy);
                unsigned newly = 0u, rem2 = pend;
                while (rem2) {
                    int x = __ffs(rem2) - 1; rem2 &= rem2 - 1;
                    if (((bal >> (4*x)) & 0xFull) == 0xFull) newly |= 1u << x;
                }
                if (!newly) { __builtin_amdgcn_s_sleep(1); continue; }
                done |= newly;
                __hip_atomic_store(&mbox, done, __ATOMIC_RELAXED,
                                   __HIP_MEMORY_SCOPE_WORKGROUP);
                asm volatile("" ::: "memory");
                unsigned go = newly;
                while (go) {
                    int x = __ffs(go) - 1; go &= go - 1;
                    int yl = (x <= px-2) ? py : ((x == px-1) ? py-1 : py-2);
                    proc_row(Eb + (size_t)(x * WW) * CC + cb, yl + 1, ar, er, hacc);
                }
                pend &= ~newly;
            }
        } else {
            while (pend) {
                unsigned d = __hip_atomic_load(&mbox, __ATOMIC_RELAXED,
                                               __HIP_MEMORY_SCOPE_WORKGROUP);
                unsigned newly = d & pend;
                if (!newly) { __builtin_amdgcn_s_sleep(2); continue; }
                asm volatile("" ::: "memory");
                unsigned go = newly;
                while (go) {
                    int x = __ffs(go) - 1; go &= go - 1;
                    int yl = (x <= px-2) ? py : ((x == px-1) ? py-1 : py-2);
                    proc_row(Eb + (size_t)(x * WW) * CC + cb, yl + 1, ar, er, hacc);
                }
                pend &= ~newly;
            }
        }

        // Phase 2: the two d-1 critical pixels; per-wave merged poll (fast path)
        __builtin_amdgcn_s_setprio(1);
        if (px > 0 || py > 0) {
            int qN = (px-1) * WW + py, qW = px * WW + (py-1);
            while (true) {
                bool rdy = true;
                if (lane < 4) {
                    if (px > 0) rdy = chk4(uflag + (size_t)qN * FW + lane * 4);
                } else if (lane < 8) {
                    if (py > 0) rdy = chk4(uflag + (size_t)qW * FW + (lane-4) * 4);
                }
                if ((__ballot(rdy) & 0xFFull) == 0xFFull) break;
                __builtin_amdgcn_s_sleep(1);
            }
            asm volatile("" ::: "memory");
            float4 n0, n1, w0, w1;
            if (px > 0) {
                const float4* ep = (const float4*)(Eb + (size_t)qN * CC + cb);
                n0 = ep[0]; n1 = ep[64];
            }
            if (py > 0) {
                const float4* ep = (const float4*)(Eb + (size_t)qW * CC + cb);
                w0 = ep[0]; w1 = ep[64];
            }
            if (px > 0) pix(n0, n1, ar, er, hacc);
            if (py > 0) pix(w0, w1, ar, er, hacc);
        }
        {   // self pixel: U=0 -> E=1
            float ds = 0.f, tl[8];
            #pragma unroll
            for (int j = 0; j < 8; ++j) {
                float pv = er[j];
                ds += fmaxf(pv, 1.0f);
                tl[j] = fmaxf(ar[j], 0.0f) * pv;
            }
            #pragma unroll
            for (int off = 32; off; off >>= 1) ds += __shfl_xor(ds, off, 64);
            float rd = 1.0f / ds;
            #pragma unroll
            for (int j = 0; j < 8; ++j) hacc[j] += tl[j] * rd;
        }

        // per-wave publish: contiguous WT stores + own drain + counter bump
        float* hp = h_t + ((size_t)cell * NSEQ + s) * CC;
        #pragma unroll
        for (int j = 0; j < 4; ++j) {
            store_wt(hp + cb + j,       hacc[j]);
            store_wt(hp + cb + 256 + j, hacc[4 + j]);
        }
        __builtin_amdgcn_s_waitcnt(0);
        asm volatile("" ::: "memory");
        if (lane == 0) atomicAdd(hcnt + (size_t)cell * FW, 1u);
    }
}

// ---------------------------------------------------------------------------
// gemm_y: Y[b][p][c] = sum_k Wo[c][k] * (sum_m h_t[p][2m+b][k]) + 4*b_out[c]
// ---------------------------------------------------------------------------
__global__ __launch_bounds__(256) void gemm_y(
    const float* __restrict__ Wo, const float* __restrict__ h_t,
    const float* __restrict__ b_out, float* __restrict__ Y) {
    __shared__ float Ws[32][33], Hs[32][33];
    int b  = blockIdx.z;
    int c0 = blockIdx.x * 32, p0 = blockIdx.y * 32;
    int t  = threadIdx.x;
    int tx = t % 32, ty = t / 32;
    int pl = (t % 16) * 2, cl = (t / 16) * 2;
    float acc[2][2] = {{0.f,0.f},{0.f,0.f}};
    for (int k0 = 0; k0 < CC; k0 += 32) {
        #pragma unroll
        for (int r = 0; r < 4; ++r)
            Ws[ty + 8*r][tx] = Wo[(size_t)(c0 + ty + 8*r) * CC + k0 + tx];
        #pragma unroll
        for (int r = 0; r < 4; ++r) {
            int p = p0 + ty + 8*r;
            float v = 0.f;
            if (p < PP) {
                size_t base = (size_t)p * NSEQ * CC + k0 + tx;
                v = h_t[base + (size_t)(0 + b) * CC]
                  + h_t[base + (size_t)(2 + b) * CC]
                  + h_t[base + (size_t)(4 + b) * CC]
                  + h_t[base + (size_t)(6 + b) * CC];
            }
            Hs[tx][ty + 8*r] = v;
        }
        __syncthreads();
        #pragma unroll
        for (int k = 0; k < 32; ++k) {
            float w0 = Ws[cl][k], w1 = Ws[cl+1][k];
            float h0 = Hs[k][pl], h1 = Hs[k][pl+1];
            acc[0][0] += w0*h0; acc[0][1] += w0*h1;
            acc[1][0] += w1*h0; acc[1][1] += w1*h1;
        }
        __syncthreads();
    }
    #pragma unroll
    for (int i = 0; i < 2; ++i)
        #pragma unroll
        for (int j = 0; j < 2; ++j) {
            int cc = c0 + cl + i, p = p0 + pl + j;
            if (p < PP) Y[((size_t)b * PP + p) * CC + cc] = acc[i][j] + 4.0f * b_out[cc];
        }
}

// ---------------------------------------------------------------------------
// softmax over channels -> out[b][c][p]
// ---------------------------------------------------------------------------
__global__ __launch_bounds__(256) void softmax_out(
    const float* __restrict__ Y, float* __restrict__ out) {
    int wave = threadIdx.x >> 6, lane = threadIdx.x & 63;
    int idx = blockIdx.x * 4 + wave;
    if (idx >= BB * PP) return;
    int b = idx / PP, p = idx % PP;
    const float* y = Y + ((size_t)b * PP + p) * CC;
    float v[8];
    float mx = -3.4e38f;
    #pragma unroll
    for (int j = 0; j < 8; ++j) { v[j] = y[lane + 64*j]; mx = fmaxf(mx, v[j]); }
    #pragma unroll
    for (int off = 32; off; off >>= 1) mx = fmaxf(mx, __shfl_xor(mx, off, 64));
    float sum = 0.f;
    #pragma unroll
    for (int j = 0; j < 8; ++j) { v[j] = expf(v[j] - mx); sum += v[j]; }
    #pragma unroll
    for (int off = 32; off; off >>= 1) sum += __shfl_xor(sum, off, 64);
    float r = 1.0f / sum;
    #pragma unroll
    for (int j = 0; j < 8; ++j)
        out[((size_t)b * CC + lane + 64*j) * PP + p] = v[j] * r;
}

// ---------------------------------------------------------------------------
extern "C" void kernel_launch(void* const* d_in, const int* in_sizes, int n_in,
                              void* d_out, int out_size, void* d_ws, size_t ws_size,
                              hipStream_t stream) {
    const float* X     = (const float*)d_in[0];
    const float* Wx    = (const float*)d_in[1];
    const float* Wh    = (const float*)d_in[2];
    const float* b_in  = (const float*)d_in[3];
    const float* Wo    = (const float*)d_in[4];
    const float* b_out = (const float*)d_in[5];
    float* out = (float*)d_out;

    float* ws  = (float*)d_ws;
    float* WhT = ws;                        // 262144
    float* A   = WhT + 262144;              // 200704
    float* E   = A   + 200704;              // 802816  [s][cell][c] = exp(U)
    float* h_t = E   + 802816;              // 802816  [cell][s][c]
    float* Y   = h_t + 802816;              // 200704
    unsigned* uflag = (unsigned*)(Y + 200704);      // PP*FW
    unsigned* hcnt  = uflag + PP * FW;              // PP*FW

    hipLaunchKernelGGL(prep, dim3(481), dim3(256), 0, stream,
                       Wx, X, b_in, Wh, A, WhT, uflag);
    hipLaunchKernelGGL(rnn_dataflow, dim3(NWORK + PP), dim3(512), 0, stream,
                       A, WhT, E, h_t, uflag, hcnt);
    hipLaunchKernelGGL(gemm_y, dim3(16, 7, 2), dim3(256), 0, stream, Wo, h_t, b_out, Y);
    hipLaunchKernelGGL(softmax_out, dim3(98), dim3(256), 0, stream, Y, out);
}

// Round 12
// 533.329 us; speedup vs baseline: 1.1809x; 1.0172x over previous
//
#include <hip/hip_runtime.h>
#include <hip/hip_bf16.h>

#define BB 2
#define CC 512
#define HH 14
#define WW 14
#define PP 196
#define NSEQ 8
#define NSLICE 8                 // worker WGs per row (64 ch each)
#define NWORK (14 * NSLICE)      // 112
#define FW 16                    // flag words per cell (one 64B line)

// ---------------------------------------------------------------------------
// prep: gemm_a (224 WGs) + transpose_wh (256 WGs) + flag zero (1 WG)
// ---------------------------------------------------------------------------
__global__ __launch_bounds__(256) void prep(
    const float* __restrict__ Wx, const float* __restrict__ X,
    const float* __restrict__ b_in, const float* __restrict__ Wh,
    float* __restrict__ A, float* __restrict__ WhT,
    unsigned* __restrict__ flags /* uflag then hcnt, contiguous */) {
    __shared__ float Ws[32][33], Xs[32][33];
    int bid = blockIdx.x;
    int t = threadIdx.x;
    if (bid < 224) {
        int z = bid / 112, rem = bid % 112;
        int c0 = (rem % 16) * 32, p0 = (rem / 16) * 32;
        int tx = t % 32, ty = t / 32;
        int pl = (t % 16) * 2, cl = (t / 16) * 2;
        float acc[2][2] = {{0.f,0.f},{0.f,0.f}};
        for (int k0 = 0; k0 < CC; k0 += 32) {
            #pragma unroll
            for (int r = 0; r < 4; ++r)
                Ws[ty + 8*r][tx] = Wx[(size_t)(c0 + ty + 8*r) * CC + k0 + tx];
            #pragma unroll
            for (int r = 0; r < 4; ++r) {
                int p = p0 + tx, k = k0 + ty + 8*r;
                Xs[ty + 8*r][tx] = (p < PP) ? X[((size_t)z * CC + k) * PP + p] : 0.f;
            }
            __syncthreads();
            #pragma unroll
            for (int k = 0; k < 32; ++k) {
                float w0 = Ws[cl][k], w1 = Ws[cl+1][k];
                float x0 = Xs[k][pl], x1 = Xs[k][pl+1];
                acc[0][0] += w0*x0; acc[0][1] += w0*x1;
                acc[1][0] += w1*x0; acc[1][1] += w1*x1;
            }
            __syncthreads();
        }
        #pragma unroll
        for (int i = 0; i < 2; ++i)
            #pragma unroll
            for (int j = 0; j < 2; ++j) {
                int c = c0 + cl + i, p = p0 + pl + j;
                if (p < PP) A[((size_t)z * PP + p) * CC + c] = acc[i][j] + b_in[c];
            }
    } else if (bid < 480) {
        int tid = bid - 224;
        int c0 = (tid % 16) * 32, k0 = (tid / 16) * 32;
        int tx = t % 32, ty = t / 32;
        #pragma unroll
        for (int r = 0; r < 4; ++r)
            Ws[ty + 8*r][tx] = Wh[(size_t)(c0 + ty + 8*r) * CC + k0 + tx];
        __syncthreads();
        #pragma unroll
        for (int r = 0; r < 4; ++r)
            WhT[(size_t)(k0 + ty + 8*r) * CC + c0 + tx] = Ws[tx][ty + 8*r];
    } else {
        for (int i = t; i < 2 * PP * FW; i += 256) flags[i] = 0u;
    }
}

// ---------------------------------------------------------------------------
// sync primitives
// ---------------------------------------------------------------------------
__device__ __forceinline__ unsigned flag_ld(const unsigned* f) {
    return __hip_atomic_load(f, __ATOMIC_RELAXED, __HIP_MEMORY_SCOPE_AGENT);
}
__device__ __forceinline__ void flag_st(unsigned* f) {
    __hip_atomic_store(f, 1u, __ATOMIC_RELAXED, __HIP_MEMORY_SCOPE_AGENT);
}
__device__ __forceinline__ void store_wt(float* p, float v) {
    __hip_atomic_store(p, v, __ATOMIC_RELAXED, __HIP_MEMORY_SCOPE_AGENT);
}
// wave-level wait: 8 slice flags on one line
__device__ __forceinline__ void wait8(const unsigned* fb, int lane) {
    while (true) {
        unsigned f = (lane < 8) ? flag_ld(fb + lane) : 1u;
        if (__ballot(f != 0u) == ~0ull) break;
        __builtin_amdgcn_s_sleep(1);
    }
    asm volatile("" ::: "memory");
}

// one window pixel for 8 channels (this wave's seq); E = exp(U) input
__device__ __forceinline__ void pix(const float4 E0, const float4 E1,
                                    const float* ar, const float* er, float* hacc) {
    float ee[8] = {E0.x,E0.y,E0.z,E0.w,E1.x,E1.y,E1.z,E1.w};
    float ds = 0.f, tl[8];
    #pragma unroll
    for (int j = 0; j < 8; ++j) {
        float sv = ar[j] + __logf(ee[j]);
        float pv = er[j] * ee[j];
        ds += fmaxf(pv, 1.0f);
        tl[j] = fmaxf(sv, 0.0f) * pv;
    }
    #pragma unroll
    for (int off = 32; off; off >>= 1) ds += __shfl_xor(ds, off, 64);
    float rd = 1.0f / ds;
    #pragma unroll
    for (int j = 0; j < 8; ++j) hacc[j] += tl[j] * rd;
}

// process n pixels at rowp + y*CC, 4-deep pipelined plain loads
__device__ __forceinline__ void proc_row(const float* __restrict__ rowp, int n,
                                         const float* ar, const float* er, float* hacc) {
    float4 cur[4][2];
    int y = 0, curn = (n < 4) ? n : 4;
    #pragma unroll
    for (int i = 0; i < 4; ++i) if (i < curn) {
        cur[i][0] = *(const float4*)(rowp + (size_t)i * CC);
        cur[i][1] = *(const float4*)(rowp + (size_t)i * CC + 256);
    }
    while (true) {
        int yn = y + curn;
        int rem = n - yn;
        int nextn = (rem < 4) ? rem : 4;
        float4 nxt[4][2];
        #pragma unroll
        for (int i = 0; i < 4; ++i) if (i < nextn) {
            nxt[i][0] = *(const float4*)(rowp + (size_t)(yn + i) * CC);
            nxt[i][1] = *(const float4*)(rowp + (size_t)(yn + i) * CC + 256);
        }
        #pragma unroll
        for (int i = 0; i < 4; ++i) if (i < curn)
            pix(cur[i][0], cur[i][1], ar, er, hacc);
        if (nextn <= 0) break;
        #pragma unroll
        for (int i = 0; i < 4; ++i) if (i < nextn) {
            cur[i][0] = nxt[i][0]; cur[i][1] = nxt[i][1];
        }
        curn = nextn; y = yn;
    }
}

// ---------------------------------------------------------------------------
// One kernel, two roles:
//   blockIdx 0..111   : row workers (row=bid>>3, 64-ch slice). Per cell they
//                       compute the critical TAIL (N/W pixels, full-channel,
//                       denominators via butterfly+LDS) AND the matvec —
//                       single fabric crossing per chain step.
//   blockIdx 112..307 : per-cell bulk WGs (self + slack>=2 pixels), off-path,
//                       publish h_bulk.
// ---------------------------------------------------------------------------
__global__ __launch_bounds__(512, 2) void rnn_dataflow(
    const float* __restrict__ A, const float* __restrict__ WhT,
    float* __restrict__ E, float* __restrict__ h_bulk,
    float* __restrict__ h_t, unsigned* __restrict__ uflag,
    unsigned* __restrict__ hcnt) {
    __shared__ float hT[CC * 9];      // full h [k][s], stride 9: conflict-free
    __shared__ float ured[64 * 9];    // matvec result [c][s]
    __shared__ float red[8][16];      // per-wave denominator partials
    __shared__ float dsf[16];         // [0..7]=North ds, [8..15]=West ds
    int bid = blockIdx.x;
    int t = threadIdx.x;
    int lane = t & 63, wv = t >> 6;

    if (bid < NWORK) {
        // ================= row worker =================
        int px = bid >> 3, w = bid & 7;
        int ksub = t & 31, quad = t >> 5;        // 32 k-lanes x 16 c-quads
        int c0 = w * 64 + quad * 4;
        float wreg[4][16];                        // 64 weight VGPRs
        #pragma unroll
        for (int ci = 0; ci < 4; ++ci)
            #pragma unroll
            for (int j = 0; j < 16; ++j)
                wreg[ci][j] = WhT[(size_t)(ksub + 32*j) * CC + c0 + ci];
        __builtin_amdgcn_s_setprio(1);

        for (int py = 0; py < WW; ++py) {
            int cell = px * WW + py;
            int cellN = cell - WW, cellW = cell - 1;

            // a / exp(a) for channel k = t, all 8 seqs (overlaps the poll)
            float av[8], er_[8];
            #pragma unroll
            for (int s = 0; s < 8; ++s) {
                int m = s >> 1, b = s & 1;
                int fi = (m & 2) ? (HH-1-px) : px, fj = (m & 1) ? (WW-1-py) : py;
                av[s] = A[((size_t)b * PP + fi * WW + fj) * CC + t];
            }
            #pragma unroll
            for (int s = 0; s < 8; ++s) er_[s] = __expf(av[s]);

            // merged poll (wave 0): N slices, W slices, h_bulk counter
            if (wv == 0) {
                const unsigned* nf = (px > 0) ? uflag + (size_t)cellN * FW : nullptr;
                const unsigned* wf = (py > 0) ? uflag + (size_t)cellW * FW : nullptr;
                while (true) {
                    unsigned f = 1u;
                    if (lane < 8)       { if (nf) f = flag_ld(nf + lane); }
                    else if (lane < 16) { if (wf) f = flag_ld(wf + (lane - 8)); }
                    else if (lane == 16) f = (flag_ld(hcnt + (size_t)cell * FW) >= 8u) ? 1u : 0u;
                    if (__ballot(f != 0u) == ~0ull) break;
                    __builtin_amdgcn_s_sleep(1);
                }
            }
            __syncthreads();
            asm volatile("" ::: "memory");

            // stage: h_bulk + full-channel E_N / E_W (coalesced, channel = t)
            float hb[8], en[8], ew[8];
            #pragma unroll
            for (int s = 0; s < 8; ++s)
                hb[s] = h_bulk[((size_t)cell * NSEQ + s) * CC + t];
            if (px > 0)
                #pragma unroll
                for (int s = 0; s < 8; ++s)
                    en[s] = E[((size_t)s * PP + cellN) * CC + t];
            if (py > 0)
                #pragma unroll
                for (int s = 0; s < 8; ++s)
                    ew[s] = E[((size_t)s * PP + cellW) * CC + t];

            // denominators for the 2 tail pixels (full-channel reductions)
            float pv[16];
            #pragma unroll
            for (int s = 0; s < 8; ++s) {
                pv[s]     = (px > 0) ? fmaxf(er_[s] * en[s], 1.f) : 0.f;
                pv[8 + s] = (py > 0) ? fmaxf(er_[s] * ew[s], 1.f) : 0.f;
            }
            #pragma unroll
            for (int off = 1; off < 64; off <<= 1)
                #pragma unroll
                for (int i = 0; i < 16; ++i) pv[i] += __shfl_xor(pv[i], off, 64);
            if (lane == 0)
                #pragma unroll
                for (int i = 0; i < 16; ++i) red[wv][i] = pv[i];
            __syncthreads();
            if (t < 16) {
                float x = 0.f;
                #pragma unroll
                for (int r = 0; r < 8; ++r) x += red[r][t];
                dsf[t] = x;
            }
            __syncthreads();

            // full h for channel t = bulk(+self) + North + West contributions
            #pragma unroll
            for (int s = 0; s < 8; ++s) {
                float h = hb[s];
                if (px > 0)
                    h += fmaxf(av[s] + __logf(en[s]), 0.f) * (er_[s] * en[s]) / dsf[s];
                if (py > 0)
                    h += fmaxf(av[s] + __logf(ew[s]), 0.f) * (er_[s] * ew[s]) / dsf[8 + s];
                hT[t * 9 + s] = h;
                if (w == 0) h_t[((size_t)cell * NSEQ + s) * CC + t] = h;  // for gemm_y
            }
            __syncthreads();
            if (cell == PP - 1) break;           // (13,13): no U consumer

            // matvec: U[c0..c0+3] over k = ksub + 32j, weights in VGPRs
            float acc[4][8];
            #pragma unroll
            for (int ci = 0; ci < 4; ++ci)
                #pragma unroll
                for (int ss = 0; ss < 8; ++ss) acc[ci][ss] = 0.f;
            #pragma unroll
            for (int j = 0; j < 16; ++j) {
                int k = ksub + 32*j;
                float hh[8];
                #pragma unroll
                for (int ss = 0; ss < 8; ++ss) hh[ss] = hT[k * 9 + ss];
                #pragma unroll
                for (int ci = 0; ci < 4; ++ci) {
                    float wvv = wreg[ci][j];
                    #pragma unroll
                    for (int ss = 0; ss < 8; ++ss) acc[ci][ss] += wvv * hh[ss];
                }
            }
            #pragma unroll
            for (int off = 1; off < 32; off <<= 1)
                #pragma unroll
                for (int ci = 0; ci < 4; ++ci)
                    #pragma unroll
                    for (int ss = 0; ss < 8; ++ss)
                        acc[ci][ss] += __shfl_xor(acc[ci][ss], off, 64);
            if (ksub == 0)
                #pragma unroll
                for (int ci = 0; ci < 4; ++ci)
                    #pragma unroll
                    for (int ss = 0; ss < 8; ++ss)
                        ured[(quad*4 + ci) * 9 + ss] = acc[ci][ss];
            __syncthreads();
            {   // publish E = exp(U): 1 coalesced WT store per thread
                int s = t >> 6, c = t & 63;
                store_wt(&E[((size_t)s * PP + cell) * CC + w*64 + c],
                         __expf(ured[c * 9 + s]));
            }
            __syncthreads();     // all waves' stores drained (vmcnt 0 @ barrier)
            if (t == 0) flag_st(uflag + (size_t)cell * FW + w);
        }
    } else {
        // ================= bulk window WG (self + slack>=2), off-path =======
        int cell = bid - NWORK;
        int px = cell / WW, py = cell % WW;
        int s = wv, m = s >> 1, b = s & 1;
        int fi = (m & 2) ? (HH-1-px) : px;
        int fj = (m & 1) ? (WW-1-py) : py;
        int cb = lane * 4;

        const float* acur = A + ((size_t)b * PP + fi * WW + fj) * CC;
        float4 a0 = *(const float4*)(acur + cb);
        float4 a1 = *(const float4*)(acur + cb + 256);
        float ar[8] = {a0.x,a0.y,a0.z,a0.w,a1.x,a1.y,a1.z,a1.w};
        float er[8];
        #pragma unroll
        for (int j = 0; j < 8; ++j) er[j] = __expf(ar[j]);
        float hacc[8] = {0.f,0.f,0.f,0.f,0.f,0.f,0.f,0.f};

        {   // self pixel first (needs no U at all): U=0 -> E=1
            float ds = 0.f, tl[8];
            #pragma unroll
            for (int j = 0; j < 8; ++j) {
                float pv = er[j];
                ds += fmaxf(pv, 1.0f);
                tl[j] = fmaxf(ar[j], 0.0f) * pv;
            }
            #pragma unroll
            for (int off = 32; off; off >>= 1) ds += __shfl_xor(ds, off, 64);
            float rd = 1.0f / ds;
            #pragma unroll
            for (int j = 0; j < 8; ++j) hacc[j] += tl[j] * rd;
        }

        const float* Eb = E + (size_t)s * PP * CC;
        // bulk rows: x<=px-2 -> y<=py ; x=px-1 -> y<=py-1 ; x=px -> y<=py-2
        for (int x = 0; x <= px; ++x) {
            int yl = (x <= px-2) ? py : ((x == px-1) ? py-1 : py-2);
            if (yl < 0) continue;
            wait8(uflag + (size_t)(x * WW + yl) * FW, lane);
            proc_row(Eb + (size_t)(x * WW) * CC + cb, yl + 1, ar, er, hacc);
        }

        // per-wave publish h_bulk: contiguous WT stores + drain + counter
        float* hp = h_bulk + ((size_t)cell * NSEQ + s) * CC;
        #pragma unroll
        for (int j = 0; j < 4; ++j) {
            store_wt(hp + cb + j,       hacc[j]);
            store_wt(hp + cb + 256 + j, hacc[4 + j]);
        }
        __builtin_amdgcn_s_waitcnt(0);
        asm volatile("" ::: "memory");
        if (lane == 0) atomicAdd(hcnt + (size_t)cell * FW, 1u);
    }
}

// ---------------------------------------------------------------------------
// gemm_y: Y[b][p][c] = sum_k Wo[c][k] * (sum_m h_t[p][2m+b][k]) + 4*b_out[c]
// ---------------------------------------------------------------------------
__global__ __launch_bounds__(256) void gemm_y(
    const float* __restrict__ Wo, const float* __restrict__ h_t,
    const float* __restrict__ b_out, float* __restrict__ Y) {
    __shared__ float Ws[32][33], Hs[32][33];
    int b  = blockIdx.z;
    int c0 = blockIdx.x * 32, p0 = blockIdx.y * 32;
    int t  = threadIdx.x;
    int tx = t % 32, ty = t / 32;
    int pl = (t % 16) * 2, cl = (t / 16) * 2;
    float acc[2][2] = {{0.f,0.f},{0.f,0.f}};
    for (int k0 = 0; k0 < CC; k0 += 32) {
        #pragma unroll
        for (int r = 0; r < 4; ++r)
            Ws[ty + 8*r][tx] = Wo[(size_t)(c0 + ty + 8*r) * CC + k0 + tx];
        #pragma unroll
        for (int r = 0; r < 4; ++r) {
            int p = p0 + ty + 8*r;
            float v = 0.f;
            if (p < PP) {
                size_t base = (size_t)p * NSEQ * CC + k0 + tx;
                v = h_t[base + (size_t)(0 + b) * CC]
                  + h_t[base + (size_t)(2 + b) * CC]
                  + h_t[base + (size_t)(4 + b) * CC]
                  + h_t[base + (size_t)(6 + b) * CC];
            }
            Hs[tx][ty + 8*r] = v;
        }
        __syncthreads();
        #pragma unroll
        for (int k = 0; k < 32; ++k) {
            float w0 = Ws[cl][k], w1 = Ws[cl+1][k];
            float h0 = Hs[k][pl], h1 = Hs[k][pl+1];
            acc[0][0] += w0*h0; acc[0][1] += w0*h1;
            acc[1][0] += w1*h0; acc[1][1] += w1*h1;
        }
        __syncthreads();
    }
    #pragma unroll
    for (int i = 0; i < 2; ++i)
        #pragma unroll
        for (int j = 0; j < 2; ++j) {
            int cc = c0 + cl + i, p = p0 + pl + j;
            if (p < PP) Y[((size_t)b * PP + p) * CC + cc] = acc[i][j] + 4.0f * b_out[cc];
        }
}

// ---------------------------------------------------------------------------
// softmax over channels -> out[b][c][p]
// ---------------------------------------------------------------------------
__global__ __launch_bounds__(256) void softmax_out(
    const float* __restrict__ Y, float* __restrict__ out) {
    int wave = threadIdx.x >> 6, lane = threadIdx.x & 63;
    int idx = blockIdx.x * 4 + wave;
    if (idx >= BB * PP) return;
    int b = idx / PP, p = idx % PP;
    const float* y = Y + ((size_t)b * PP + p) * CC;
    float v[8];
    float mx = -3.4e38f;
    #pragma unroll
    for (int j = 0; j < 8; ++j) { v[j] = y[lane + 64*j]; mx = fmaxf(mx, v[j]); }
    #pragma unroll
    for (int off = 32; off; off >>= 1) mx = fmaxf(mx, __shfl_xor(mx, off, 64));
    float sum = 0.f;
    #pragma unroll
    for (int j = 0; j < 8; ++j) { v[j] = expf(v[j] - mx); sum += v[j]; }
    #pragma unroll
    for (int off = 32; off; off >>= 1) sum += __shfl_xor(sum, off, 64);
    float r = 1.0f / sum;
    #pragma unroll
    for (int j = 0; j < 8; ++j)
        out[((size_t)b * CC + lane + 64*j) * PP + p] = v[j] * r;
}

// ---------------------------------------------------------------------------
extern "C" void kernel_launch(void* const* d_in, const int* in_sizes, int n_in,
                              void* d_out, int out_size, void* d_ws, size_t ws_size,
                              hipStream_t stream) {
    const float* X     = (const float*)d_in[0];
    const float* Wx    = (const float*)d_in[1];
    const float* Wh    = (const float*)d_in[2];
    const float* b_in  = (const float*)d_in[3];
    const float* Wo    = (const float*)d_in[4];
    const float* b_out = (const float*)d_in[5];
    float* out = (float*)d_out;

    float* ws     = (float*)d_ws;
    float* WhT    = ws;                     // 262144
    float* A      = WhT    + 262144;        // 200704
    float* E      = A      + 200704;        // 802816  [s][cell][c] = exp(U)
    float* h_bulk = E      + 802816;        // 802816  [cell][s][c]
    float* h_t    = h_bulk + 802816;        // 802816  [cell][s][c] full h
    float* Y      = h_t    + 802816;        // 200704
    unsigned* uflag = (unsigned*)(Y + 200704);      // PP*FW
    unsigned* hcnt  = uflag + PP * FW;              // PP*FW

    hipLaunchKernelGGL(prep, dim3(481), dim3(256), 0, stream,
                       Wx, X, b_in, Wh, A, WhT, uflag);
    hipLaunchKernelGGL(rnn_dataflow, dim3(NWORK + PP), dim3(512), 0, stream,
                       A, WhT, E, h_bulk, h_t, uflag, hcnt);
    hipLaunchKernelGGL(gemm_y, dim3(16, 7, 2), dim3(256), 0, stream, Wo, h_t, b_out, Y);
    hipLaunchKernelGGL(softmax_out, dim3(98), dim3(256), 0, stream, Y, out);
}

// Round 13
// 510.520 us; speedup vs baseline: 1.2336x; 1.0447x over previous
//
#include <hip/hip_runtime.h>
#include <hip/hip_bf16.h>

#define BB 2
#define CC 512
#define HH 14
#define WW 14
#define PP 196
#define NSEQ 8
#define NSLICE 8                 // worker WGs per row (64 ch each)
#define NWORK (14 * NSLICE)      // 112
#define FW 16                    // words per counter line (64B)

// counters: ucnt[cell*FW] counts slice publishes (8 = E ready)
//           hcnt[cell*FW] counts bulk-window wave publishes (8 = h_bulk ready)

// ---------------------------------------------------------------------------
// prep: gemm_a (224 WGs) + transpose_wh (256 WGs) + counter zero (1 WG)
// ---------------------------------------------------------------------------
__global__ __launch_bounds__(256) void prep(
    const float* __restrict__ Wx, const float* __restrict__ X,
    const float* __restrict__ b_in, const float* __restrict__ Wh,
    float* __restrict__ A, float* __restrict__ WhT,
    unsigned* __restrict__ cnts /* ucnt then hcnt, contiguous */) {
    __shared__ float Ws[32][33], Xs[32][33];
    int bid = blockIdx.x;
    int t = threadIdx.x;
    if (bid < 224) {
        int z = bid / 112, rem = bid % 112;
        int c0 = (rem % 16) * 32, p0 = (rem / 16) * 32;
        int tx = t % 32, ty = t / 32;
        int pl = (t % 16) * 2, cl = (t / 16) * 2;
        float acc[2][2] = {{0.f,0.f},{0.f,0.f}};
        for (int k0 = 0; k0 < CC; k0 += 32) {
            #pragma unroll
            for (int r = 0; r < 4; ++r)
                Ws[ty + 8*r][tx] = Wx[(size_t)(c0 + ty + 8*r) * CC + k0 + tx];
            #pragma unroll
            for (int r = 0; r < 4; ++r) {
                int p = p0 + tx, k = k0 + ty + 8*r;
                Xs[ty + 8*r][tx] = (p < PP) ? X[((size_t)z * CC + k) * PP + p] : 0.f;
            }
            __syncthreads();
            #pragma unroll
            for (int k = 0; k < 32; ++k) {
                float w0 = Ws[cl][k], w1 = Ws[cl+1][k];
                float x0 = Xs[k][pl], x1 = Xs[k][pl+1];
                acc[0][0] += w0*x0; acc[0][1] += w0*x1;
                acc[1][0] += w1*x0; acc[1][1] += w1*x1;
            }
            __syncthreads();
        }
        #pragma unroll
        for (int i = 0; i < 2; ++i)
            #pragma unroll
            for (int j = 0; j < 2; ++j) {
                int c = c0 + cl + i, p = p0 + pl + j;
                if (p < PP) A[((size_t)z * PP + p) * CC + c] = acc[i][j] + b_in[c];
            }
    } else if (bid < 480) {
        int tid = bid - 224;
        int c0 = (tid % 16) * 32, k0 = (tid / 16) * 32;
        int tx = t % 32, ty = t / 32;
        #pragma unroll
        for (int r = 0; r < 4; ++r)
            Ws[ty + 8*r][tx] = Wh[(size_t)(c0 + ty + 8*r) * CC + k0 + tx];
        __syncthreads();
        #pragma unroll
        for (int r = 0; r < 4; ++r)
            WhT[(size_t)(k0 + ty + 8*r) * CC + c0 + tx] = Ws[tx][ty + 8*r];
    } else {
        for (int i = t; i < 2 * PP * FW; i += 256) cnts[i] = 0u;
    }
}

// ---------------------------------------------------------------------------
// sync primitives
// ---------------------------------------------------------------------------
__device__ __forceinline__ unsigned flag_ld(const unsigned* f) {
    return __hip_atomic_load(f, __ATOMIC_RELAXED, __HIP_MEMORY_SCOPE_AGENT);
}
__device__ __forceinline__ void store_wt(float* p, float v) {
    __hip_atomic_store(p, v, __ATOMIC_RELAXED, __HIP_MEMORY_SCOPE_AGENT);
}

// one window pixel for 8 channels (this wave's seq); E = exp(U) input
__device__ __forceinline__ void pix(const float4 E0, const float4 E1,
                                    const float* ar, const float* er, float* hacc) {
    float ee[8] = {E0.x,E0.y,E0.z,E0.w,E1.x,E1.y,E1.z,E1.w};
    float ds = 0.f, tl[8];
    #pragma unroll
    for (int j = 0; j < 8; ++j) {
        float sv = ar[j] + __logf(ee[j]);
        float pv = er[j] * ee[j];
        ds += fmaxf(pv, 1.0f);
        tl[j] = fmaxf(sv, 0.0f) * pv;
    }
    #pragma unroll
    for (int off = 32; off; off >>= 1) ds += __shfl_xor(ds, off, 64);
    float rd = 1.0f / ds;
    #pragma unroll
    for (int j = 0; j < 8; ++j) hacc[j] += tl[j] * rd;
}

// process n pixels at rowp + y*CC, 4-deep pipelined plain loads
__device__ __forceinline__ void proc_row(const float* __restrict__ rowp, int n,
                                         const float* ar, const float* er, float* hacc) {
    float4 cur[4][2];
    int y = 0, curn = (n < 4) ? n : 4;
    #pragma unroll
    for (int i = 0; i < 4; ++i) if (i < curn) {
        cur[i][0] = *(const float4*)(rowp + (size_t)i * CC);
        cur[i][1] = *(const float4*)(rowp + (size_t)i * CC + 256);
    }
    while (true) {
        int yn = y + curn;
        int rem = n - yn;
        int nextn = (rem < 4) ? rem : 4;
        float4 nxt[4][2];
        #pragma unroll
        for (int i = 0; i < 4; ++i) if (i < nextn) {
            nxt[i][0] = *(const float4*)(rowp + (size_t)(yn + i) * CC);
            nxt[i][1] = *(const float4*)(rowp + (size_t)(yn + i) * CC + 256);
        }
        #pragma unroll
        for (int i = 0; i < 4; ++i) if (i < curn)
            pix(cur[i][0], cur[i][1], ar, er, hacc);
        if (nextn <= 0) break;
        #pragma unroll
        for (int i = 0; i < 4; ++i) if (i < nextn) {
            cur[i][0] = nxt[i][0]; cur[i][1] = nxt[i][1];
        }
        curn = nextn; y = yn;
    }
}

// ---------------------------------------------------------------------------
// One kernel, two roles:
//   blockIdx 0..111   : row workers (row=bid>>3, 64-ch slice): critical tail
//                       (N/W pixels) + matvec. ONE poll lane per counter.
//   blockIdx 112..307 : per-cell bulk WGs (self + slack>=2 pixels). Wave 0 is
//                       the sole fabric poller; waves 1-7 spin on LDS mailbox.
// ---------------------------------------------------------------------------
__global__ __launch_bounds__(512, 2) void rnn_dataflow(
    const float* __restrict__ A, const float* __restrict__ WhT,
    float* __restrict__ E, float* __restrict__ h_bulk,
    float* __restrict__ h_t, unsigned* __restrict__ ucnt,
    unsigned* __restrict__ hcnt) {
    __shared__ float hT[CC * 9];      // full h [k][s], stride 9: conflict-free
    __shared__ float ured[64 * 9];    // matvec result [c][s]
    __shared__ float red[8][16];      // per-wave denominator partials
    __shared__ float dsf[16];         // [0..7]=North ds, [8..15]=West ds
    __shared__ unsigned mbox;         // bulk WG: ready-rows bitmap
    int bid = blockIdx.x;
    int t = threadIdx.x;
    int lane = t & 63, wv = t >> 6;

    if (bid < NWORK) {
        // ================= row worker =================
        int px = bid >> 3, w = bid & 7;
        int ksub = t & 31, quad = t >> 5;        // 32 k-lanes x 16 c-quads
        int c0 = w * 64 + quad * 4;
        float wreg[4][16];                        // 64 weight VGPRs
        #pragma unroll
        for (int ci = 0; ci < 4; ++ci)
            #pragma unroll
            for (int j = 0; j < 16; ++j)
                wreg[ci][j] = WhT[(size_t)(ksub + 32*j) * CC + c0 + ci];
        __builtin_amdgcn_s_setprio(1);

        for (int py = 0; py < WW; ++py) {
            int cell = px * WW + py;
            int cellN = cell - WW, cellW = cell - 1;

            // a / exp(a) for channel k = t, all 8 seqs (overlaps the poll)
            float av[8], er_[8];
            #pragma unroll
            for (int s = 0; s < 8; ++s) {
                int m = s >> 1, b = s & 1;
                int fi = (m & 2) ? (HH-1-px) : px, fj = (m & 1) ? (WW-1-py) : py;
                av[s] = A[((size_t)b * PP + fi * WW + fj) * CC + t];
            }
            #pragma unroll
            for (int s = 0; s < 8; ++s) er_[s] = __expf(av[s]);

            // merged poll: ONE lane per counter (lanes 0:N, 1:W, 2:h_bulk)
            if (wv == 0) {
                while (true) {
                    unsigned ok = 1u;
                    if (lane == 0)      { if (px > 0) ok = (flag_ld(ucnt + (size_t)cellN * FW) >= 8u); }
                    else if (lane == 1) { if (py > 0) ok = (flag_ld(ucnt + (size_t)cellW * FW) >= 8u); }
                    else if (lane == 2) ok = (flag_ld(hcnt + (size_t)cell * FW) >= 8u);
                    if (__ballot(ok != 0u) == ~0ull) break;
                    __builtin_amdgcn_s_sleep(1);
                }
            }
            __syncthreads();
            asm volatile("" ::: "memory");

            // stage: h_bulk + full-channel E_N / E_W (coalesced, channel = t)
            float hb[8], en[8], ew[8];
            #pragma unroll
            for (int s = 0; s < 8; ++s)
                hb[s] = h_bulk[((size_t)cell * NSEQ + s) * CC + t];
            if (px > 0)
                #pragma unroll
                for (int s = 0; s < 8; ++s)
                    en[s] = E[((size_t)s * PP + cellN) * CC + t];
            if (py > 0)
                #pragma unroll
                for (int s = 0; s < 8; ++s)
                    ew[s] = E[((size_t)s * PP + cellW) * CC + t];

            // denominators for the 2 tail pixels (full-channel reductions)
            float pv[16];
            #pragma unroll
            for (int s = 0; s < 8; ++s) {
                pv[s]     = (px > 0) ? fmaxf(er_[s] * en[s], 1.f) : 0.f;
                pv[8 + s] = (py > 0) ? fmaxf(er_[s] * ew[s], 1.f) : 0.f;
            }
            #pragma unroll
            for (int off = 1; off < 64; off <<= 1)
                #pragma unroll
                for (int i = 0; i < 16; ++i) pv[i] += __shfl_xor(pv[i], off, 64);
            if (lane == 0)
                #pragma unroll
                for (int i = 0; i < 16; ++i) red[wv][i] = pv[i];
            __syncthreads();
            if (t < 16) {
                float x = 0.f;
                #pragma unroll
                for (int r = 0; r < 8; ++r) x += red[r][t];
                dsf[t] = x;
            }
            __syncthreads();

            // full h for channel t = bulk(+self) + North + West contributions
            #pragma unroll
            for (int s = 0; s < 8; ++s) {
                float h = hb[s];
                if (px > 0)
                    h += fmaxf(av[s] + __logf(en[s]), 0.f) * (er_[s] * en[s]) / dsf[s];
                if (py > 0)
                    h += fmaxf(av[s] + __logf(ew[s]), 0.f) * (er_[s] * ew[s]) / dsf[8 + s];
                hT[t * 9 + s] = h;
                if (w == 0) h_t[((size_t)cell * NSEQ + s) * CC + t] = h;  // for gemm_y
            }
            __syncthreads();
            if (cell == PP - 1) break;           // (13,13): no U consumer

            // matvec: U[c0..c0+3] over k = ksub + 32j, weights in VGPRs
            float acc[4][8];
            #pragma unroll
            for (int ci = 0; ci < 4; ++ci)
                #pragma unroll
                for (int ss = 0; ss < 8; ++ss) acc[ci][ss] = 0.f;
            #pragma unroll
            for (int j = 0; j < 16; ++j) {
                int k = ksub + 32*j;
                float hh[8];
                #pragma unroll
                for (int ss = 0; ss < 8; ++ss) hh[ss] = hT[k * 9 + ss];
                #pragma unroll
                for (int ci = 0; ci < 4; ++ci) {
                    float wvv = wreg[ci][j];
                    #pragma unroll
                    for (int ss = 0; ss < 8; ++ss) acc[ci][ss] += wvv * hh[ss];
                }
            }
            #pragma unroll
            for (int off = 1; off < 32; off <<= 1)
                #pragma unroll
                for (int ci = 0; ci < 4; ++ci)
                    #pragma unroll
                    for (int ss = 0; ss < 8; ++ss)
                        acc[ci][ss] += __shfl_xor(acc[ci][ss], off, 64);
            if (ksub == 0)
                #pragma unroll
                for (int ci = 0; ci < 4; ++ci)
                    #pragma unroll
                    for (int ss = 0; ss < 8; ++ss)
                        ured[(quad*4 + ci) * 9 + ss] = acc[ci][ss];
            __syncthreads();
            {   // publish E = exp(U): 1 coalesced WT store per thread
                int s = t >> 6, c = t & 63;
                store_wt(&E[((size_t)s * PP + cell) * CC + w*64 + c],
                         __expf(ured[c * 9 + s]));
            }
            __syncthreads();     // all waves' stores drained (vmcnt 0 @ barrier)
            if (t == 0) atomicAdd(ucnt + (size_t)cell * FW, 1u);
        }
    } else {
        // ================= bulk window WG (self + slack>=2), off-path =======
        int cell = bid - NWORK;
        int px = cell / WW, py = cell % WW;
        int s = wv, m = s >> 1, b = s & 1;
        int fi = (m & 2) ? (HH-1-px) : px;
        int fj = (m & 1) ? (WW-1-py) : py;
        int cb = lane * 4;

        if (t == 0) mbox = 0u;
        __syncthreads();          // once, at WG start (long before deps ready)

        const float* acur = A + ((size_t)b * PP + fi * WW + fj) * CC;
        float4 a0 = *(const float4*)(acur + cb);
        float4 a1 = *(const float4*)(acur + cb + 256);
        float ar[8] = {a0.x,a0.y,a0.z,a0.w,a1.x,a1.y,a1.z,a1.w};
        float er[8];
        #pragma unroll
        for (int j = 0; j < 8; ++j) er[j] = __expf(ar[j]);
        float hacc[8] = {0.f,0.f,0.f,0.f,0.f,0.f,0.f,0.f};

        {   // self pixel first (needs no U at all): U=0 -> E=1
            float ds = 0.f, tl[8];
            #pragma unroll
            for (int j = 0; j < 8; ++j) {
                float pv = er[j];
                ds += fmaxf(pv, 1.0f);
                tl[j] = fmaxf(ar[j], 0.0f) * pv;
            }
            #pragma unroll
            for (int off = 32; off; off >>= 1) ds += __shfl_xor(ds, off, 64);
            float rd = 1.0f / ds;
            #pragma unroll
            for (int j = 0; j < 8; ++j) hacc[j] += tl[j] * rd;
        }

        const float* Eb = E + (size_t)s * PP * CC;
        // bulk rows: x<=px-2 -> y<=py ; x=px-1 -> y<=py-1 ; x=px -> y<=py-2
        unsigned pend = 0u;
        for (int x = 0; x <= px; ++x) {
            int yl = (x <= px-2) ? py : ((x == px-1) ? py-1 : py-2);
            if (yl >= 0) pend |= (1u << x);
        }
        if (wv == 0) {
            // sole fabric poller: lane r checks row r's tail counter
            unsigned done = 0u;
            while (pend) {
                bool rdy = true;
                if (lane <= px && (pend & (1u << lane))) {
                    int yl = (lane <= px-2) ? py : ((lane == px-1) ? py-1 : py-2);
                    rdy = flag_ld(ucnt + (size_t)(lane * WW + yl) * FW) >= 8u;
                }
                unsigned long long bal = __ballot(rdy);
                unsigned newly = 0u, rem2 = pend;
                while (rem2) {
                    int x = __ffs(rem2) - 1; rem2 &= rem2 - 1;
                    if ((bal >> x) & 1ull) newly |= 1u << x;
                }
                if (!newly) { __builtin_amdgcn_s_sleep(2); continue; }
                done |= newly;
                __hip_atomic_store(&mbox, done, __ATOMIC_RELAXED,
                                   __HIP_MEMORY_SCOPE_WORKGROUP);
                asm volatile("" ::: "memory");
                unsigned go = newly;
                while (go) {
                    int x = __ffs(go) - 1; go &= go - 1;
                    int yl = (x <= px-2) ? py : ((x == px-1) ? py-1 : py-2);
                    proc_row(Eb + (size_t)(x * WW) * CC + cb, yl + 1, ar, er, hacc);
                }
                pend &= ~newly;
            }
        } else {
            while (pend) {
                unsigned d = __hip_atomic_load(&mbox, __ATOMIC_RELAXED,
                                               __HIP_MEMORY_SCOPE_WORKGROUP);
                unsigned newly = d & pend;
                if (!newly) { __builtin_amdgcn_s_sleep(2); continue; }
                asm volatile("" ::: "memory");
                unsigned go = newly;
                while (go) {
                    int x = __ffs(go) - 1; go &= go - 1;
                    int yl = (x <= px-2) ? py : ((x == px-1) ? py-1 : py-2);
                    proc_row(Eb + (size_t)(x * WW) * CC + cb, yl + 1, ar, er, hacc);
                }
                pend &= ~newly;
            }
        }

        // per-wave publish h_bulk: contiguous WT stores + drain + counter
        float* hp = h_bulk + ((size_t)cell * NSEQ + s) * CC;
        #pragma unroll
        for (int j = 0; j < 4; ++j) {
            store_wt(hp + cb + j,       hacc[j]);
            store_wt(hp + cb + 256 + j, hacc[4 + j]);
        }
        __builtin_amdgcn_s_waitcnt(0);
        asm volatile("" ::: "memory");
        if (lane == 0) atomicAdd(hcnt + (size_t)cell * FW, 1u);
    }
}

// ---------------------------------------------------------------------------
// gemm_y: Y[b][p][c] = sum_k Wo[c][k] * (sum_m h_t[p][2m+b][k]) + 4*b_out[c]
// ---------------------------------------------------------------------------
__global__ __launch_bounds__(256) void gemm_y(
    const float* __restrict__ Wo, const float* __restrict__ h_t,
    const float* __restrict__ b_out, float* __restrict__ Y) {
    __shared__ float Ws[32][33], Hs[32][33];
    int b  = blockIdx.z;
    int c0 = blockIdx.x * 32, p0 = blockIdx.y * 32;
    int t  = threadIdx.x;
    int tx = t % 32, ty = t / 32;
    int pl = (t % 16) * 2, cl = (t / 16) * 2;
    float acc[2][2] = {{0.f,0.f},{0.f,0.f}};
    for (int k0 = 0; k0 < CC; k0 += 32) {
        #pragma unroll
        for (int r = 0; r < 4; ++r)
            Ws[ty + 8*r][tx] = Wo[(size_t)(c0 + ty + 8*r) * CC + k0 + tx];
        #pragma unroll
        for (int r = 0; r < 4; ++r) {
            int p = p0 + ty + 8*r;
            float v = 0.f;
            if (p < PP) {
                size_t base = (size_t)p * NSEQ * CC + k0 + tx;
                v = h_t[base + (size_t)(0 + b) * CC]
                  + h_t[base + (size_t)(2 + b) * CC]
                  + h_t[base + (size_t)(4 + b) * CC]
                  + h_t[base + (size_t)(6 + b) * CC];
            }
            Hs[tx][ty + 8*r] = v;
        }
        __syncthreads();
        #pragma unroll
        for (int k = 0; k < 32; ++k) {
            float w0 = Ws[cl][k], w1 = Ws[cl+1][k];
            float h0 = Hs[k][pl], h1 = Hs[k][pl+1];
            acc[0][0] += w0*h0; acc[0][1] += w0*h1;
            acc[1][0] += w1*h0; acc[1][1] += w1*h1;
        }
        __syncthreads();
    }
    #pragma unroll
    for (int i = 0; i < 2; ++i)
        #pragma unroll
        for (int j = 0; j < 2; ++j) {
            int cc = c0 + cl + i, p = p0 + pl + j;
            if (p < PP) Y[((size_t)b * PP + p) * CC + cc] = acc[i][j] + 4.0f * b_out[cc];
        }
}

// ---------------------------------------------------------------------------
// softmax over channels -> out[b][c][p]
// ---------------------------------------------------------------------------
__global__ __launch_bounds__(256) void softmax_out(
    const float* __restrict__ Y, float* __restrict__ out) {
    int wave = threadIdx.x >> 6, lane = threadIdx.x & 63;
    int idx = blockIdx.x * 4 + wave;
    if (idx >= BB * PP) return;
    int b = idx / PP, p = idx % PP;
    const float* y = Y + ((size_t)b * PP + p) * CC;
    float v[8];
    float mx = -3.4e38f;
    #pragma unroll
    for (int j = 0; j < 8; ++j) { v[j] = y[lane + 64*j]; mx = fmaxf(mx, v[j]); }
    #pragma unroll
    for (int off = 32; off; off >>= 1) mx = fmaxf(mx, __shfl_xor(mx, off, 64));
    float sum = 0.f;
    #pragma unroll
    for (int j = 0; j < 8; ++j) { v[j] = expf(v[j] - mx); sum += v[j]; }
    #pragma unroll
    for (int off = 32; off; off >>= 1) sum += __shfl_xor(sum, off, 64);
    float r = 1.0f / sum;
    #pragma unroll
    for (int j = 0; j < 8; ++j)
        out[((size_t)b * CC + lane + 64*j) * PP + p] = v[j] * r;
}

// ---------------------------------------------------------------------------
extern "C" void kernel_launch(void* const* d_in, const int* in_sizes, int n_in,
                              void* d_out, int out_size, void* d_ws, size_t ws_size,
                              hipStream_t stream) {
    const float* X     = (const float*)d_in[0];
    const float* Wx    = (const float*)d_in[1];
    const float* Wh    = (const float*)d_in[2];
    const float* b_in  = (const float*)d_in[3];
    const float* Wo    = (const float*)d_in[4];
    const float* b_out = (const float*)d_in[5];
    float* out = (float*)d_out;

    float* ws     = (float*)d_ws;
    float* WhT    = ws;                     // 262144
    float* A      = WhT    + 262144;        // 200704
    float* E      = A      + 200704;        // 802816  [s][cell][c] = exp(U)
    float* h_bulk = E      + 802816;        // 802816  [cell][s][c]
    float* h_t    = h_bulk + 802816;        // 802816  [cell][s][c] full h
    float* Y      = h_t    + 802816;        // 200704
    unsigned* ucnt = (unsigned*)(Y + 200704);       // PP*FW
    unsigned* hcnt = ucnt + PP * FW;                // PP*FW

    hipLaunchKernelGGL(prep, dim3(481), dim3(256), 0, stream,
                       Wx, X, b_in, Wh, A, WhT, ucnt);
    hipLaunchKernelGGL(rnn_dataflow, dim3(NWORK + PP), dim3(512), 0, stream,
                       A, WhT, E, h_bulk, h_t, ucnt, hcnt);
    hipLaunchKernelGGL(gemm_y, dim3(16, 7, 2), dim3(256), 0, stream, Wo, h_t, b_out, Y);
    hipLaunchKernelGGL(softmax_out, dim3(98), dim3(256), 0, stream, Y, out);
}